// Round 1
// baseline (1112.327 us; speedup 1.0000x reference)
//
#include <hip/hip_runtime.h>
#include <math.h>

#define IMG_H 256
#define IMG_W 256
#define NBATCH 32
#define NPER 4096
#define NPTS (NBATCH * NPER)

// 8 views, rows 0..2 of M (row 3 is [0,0,0,1] -> w==1 always).
// m[v][r*4+c]: hom_r = m0*x + m1*y + m2*z + m3
struct Mats { float m[8][12]; };

static void build_mats(float out[8][12]) {
  static const double EYES[8][3] = {
    {-1,-1,-1},{-1,-1, 1},{-1, 1,-1},{-1, 1, 1},
    { 1,-1,-1},{ 1,-1, 1},{ 1, 1,-1},{ 1, 1, 1}};
  for (int v = 0; v < 8; ++v) {
    const double* e = EYES[v];
    double en = sqrt(e[0]*e[0] + e[1]*e[1] + e[2]*e[2]);
    if (en < 1e-6) en = 1e-6;
    double z[3] = {e[0]/en, e[1]/en, e[2]/en};
    // x = cross(ups=(0,0,1), z) = (-z1, z0, 0)
    double x[3] = {-z[1], z[0], 0.0};
    double xn = sqrt(x[0]*x[0] + x[1]*x[1]);
    if (xn < 1e-6) xn = 1e-6;
    x[0] /= xn; x[1] /= xn; x[2] = 0.0;
    // y = cross(z, x)
    double y[3] = {z[1]*x[2] - z[2]*x[1],
                   z[2]*x[0] - z[0]*x[2],
                   z[0]*x[1] - z[1]*x[0]};
    const double s  = 1.5;
    const double pz = -2.0 / (10.0 - 0.1);
    const double c3 = (10.0 + 0.1) / (10.0 - 0.1);
    double dxe = x[0]*e[0] + x[1]*e[1] + x[2]*e[2];
    double dye = y[0]*e[0] + y[1]*e[1] + y[2]*e[2];
    double dze = z[0]*e[0] + z[1]*e[1] + z[2]*e[2];
    out[v][0] = (float)(s*x[0]); out[v][1] = (float)(s*x[1]);
    out[v][2] = (float)(s*x[2]); out[v][3] = (float)(-s*dxe);
    out[v][4] = (float)(s*y[0]); out[v][5] = (float)(s*y[1]);
    out[v][6] = (float)(s*y[2]); out[v][7] = (float)(-s*dye);
    out[v][8] = (float)(pz*z[0]); out[v][9] = (float)(pz*z[1]);
    out[v][10] = (float)(pz*z[2]); out[v][11] = (float)(-pz*dze + c3);
  }
}

// monotone float<->uint order mapping (handles negatives)
__device__ __forceinline__ unsigned int ord_f32(float f) {
  unsigned int u = __float_as_uint(f);
  return (u & 0x80000000u) ? ~u : (u | 0x80000000u);
}
__device__ __forceinline__ float unord_f32(unsigned int u) {
  return (u & 0x80000000u) ? __uint_as_float(u ^ 0x80000000u)
                           : __uint_as_float(~u);
}

__global__ void init_ws(unsigned int* ws) {
  ws[0] = 0xFFFFFFFFu;  // running-min slot (ordered): identity = max uint
  ws[1] = 0u;           // running-max slot (ordered): identity = 0
}

__global__ __launch_bounds__(256)
void zminmax_kernel(const float* __restrict__ data,
                    const int* __restrict__ view_id,
                    Mats mats, unsigned int* __restrict__ ws) {
  const int v = (*view_id) & 7;
  const float* M = mats.m[v];
  float zmin = INFINITY, zmax = -INFINITY;
  for (int p = blockIdx.x * blockDim.x + threadIdx.x; p < NPTS;
       p += gridDim.x * blockDim.x) {
    float x = data[3*p+0], y = data[3*p+1], zz = data[3*p+2];
    float z = M[8]*x + M[9]*y + M[10]*zz + M[11];
    zmin = fminf(zmin, z);
    zmax = fmaxf(zmax, z);
  }
#pragma unroll
  for (int m = 32; m >= 1; m >>= 1) {
    zmin = fminf(zmin, __shfl_xor(zmin, m, 64));
    zmax = fmaxf(zmax, __shfl_xor(zmax, m, 64));
  }
  if ((threadIdx.x & 63) == 0) {
    atomicMin(&ws[0], ord_f32(zmin));
    atomicMax(&ws[1], ord_f32(zmax));
  }
}

__global__ __launch_bounds__(256)
void splat_kernel(const float* __restrict__ data,
                  const int* __restrict__ view_id,
                  Mats mats, const unsigned int* __restrict__ ws,
                  unsigned int* __restrict__ out) {
  const int p = blockIdx.x * blockDim.x + threadIdx.x;
  if (p >= NPTS) return;
  const int v = (*view_id) & 7;
  const float* M = mats.m[v];

  float x = data[3*p+0], y = data[3*p+1], zz = data[3*p+2];
  float h0 = M[0]*x + M[1]*y + M[2]*zz + M[3];
  float h1 = M[4]*x + M[5]*y + M[6]*zz + M[7];
  float h2 = M[8]*x + M[9]*y + M[10]*zz + M[11];
  // w == 1 (row 3 of M is [0,0,0,1])

  // pos_ij = (-h1, h0); pts = (pos*0.5+0.5)*(dim-1)
  float pif = (-h1 * 0.5f + 0.5f) * (float)(IMG_H - 1);
  float pjf = ( h0 * 0.5f + 0.5f) * (float)(IMG_W - 1);

  float zmin = unord_f32(ws[0]);
  float zmax = unord_f32(ws[1]);
  float feat = 1.0f - (h2 - zmin) / (zmax - zmin);

  int base_i = (int)floorf(pif);
  int base_j = (int)floorf(pjf);
  const int b = p / NPER;
  unsigned int* outb = out + (size_t)b * IMG_H * IMG_W;

  const float kc = (float)(M_PI / 2.0 / 10.0);  // pi/2/radius
#pragma unroll 1
  for (int di = -10; di <= 11; ++di) {
    int pi = base_i + di;
    if (pi < 0 || pi >= IMG_H) continue;
    float dx = (float)pi - pif;
    float dx2 = dx * dx;
    if (dx2 > 100.0f) continue;
    unsigned int* row = outb + pi * IMG_W;
#pragma unroll 1
    for (int dj = -10; dj <= 11; ++dj) {
      int pj = base_j + dj;
      if (pj < 0 || pj >= IMG_W) continue;
      float dy = (float)pj - pjf;
      float d2 = dx2 + dy * dy;
      if (d2 > 100.0f) continue;
      float w = __cosf(sqrtf(d2) * kc);
      float val = w * feat;
      // nonneg-float bit pattern is order-preserving; guard val>0 so
      // float-roundoff negative cos at d~=radius can't poison the max.
      if (val > 0.0f) atomicMax(row + pj, __float_as_uint(val));
    }
  }
}

extern "C" void kernel_launch(void* const* d_in, const int* in_sizes, int n_in,
                              void* d_out, int out_size, void* d_ws, size_t ws_size,
                              hipStream_t stream) {
  const float* data = (const float*)d_in[0];
  const int* view_id = (const int*)d_in[1];
  unsigned int* out = (unsigned int*)d_out;
  unsigned int* ws = (unsigned int*)d_ws;

  Mats mats;
  build_mats(mats.m);

  hipMemsetAsync(d_out, 0, (size_t)out_size * sizeof(float), stream);
  init_ws<<<1, 1, 0, stream>>>(ws);
  zminmax_kernel<<<128, 256, 0, stream>>>(data, view_id, mats, ws);
  splat_kernel<<<(NPTS + 255) / 256, 256, 0, stream>>>(data, view_id, mats, ws, out);
}